// Round 1
// baseline (260.550 us; speedup 1.0000x reference)
//
#include <hip/hip_runtime.h>

typedef __bf16 bf16;
typedef __attribute__((ext_vector_type(8))) bf16 bf16x8;
typedef __attribute__((ext_vector_type(4))) float f32x4;

// async global->LDS (wave-uniform LDS base + lane*size; our lds addrs are base + tid*16)
#define GLDS16(g, l) __builtin_amdgcn_global_load_lds( \
    (const __attribute__((address_space(1))) void*)(g), \
    (__attribute__((address_space(3))) void*)(l), 16, 0, 0)
#define GLDS4(g, l) __builtin_amdgcn_global_load_lds( \
    (const __attribute__((address_space(1))) void*)(g), \
    (__attribute__((address_space(3))) void*)(l), 4, 0, 0)

// log2(e)/sqrt(128): folded into q at the QKV epilogue so softmax uses exp2 directly
#define QSCALE 0.12751744f

// ---------------------------------------------------------------- convert f32->bf16
__global__ __launch_bounds__(256) void convert_kernel(
    const float* __restrict__ x, const float* __restrict__ wq,
    const float* __restrict__ wk, const float* __restrict__ wv,
    const float* __restrict__ wp,
    bf16* __restrict__ xb, bf16* __restrict__ wqkvb, bf16* __restrict__ wpb)
{
    int bid = blockIdx.x;
    const float* src; bf16* dst; int base;
    if (bid < 4096)      { src = x;  dst = xb;              base = bid * 2048; }
    else if (bid < 4608) { src = wq; dst = wqkvb;           base = (bid - 4096) * 2048; }
    else if (bid < 5120) { src = wk; dst = wqkvb + 1048576; base = (bid - 4608) * 2048; }
    else if (bid < 5632) { src = wv; dst = wqkvb + 2097152; base = (bid - 5120) * 2048; }
    else                 { src = wp; dst = wpb;             base = (bid - 5632) * 2048; }
    int i = base + threadIdx.x * 8;
    const f32x4* s4 = (const f32x4*)(src + i);
    f32x4 a = s4[0], c = s4[1];
    bf16x8 v;
    #pragma unroll
    for (int e = 0; e < 4; ++e) { v[e] = (bf16)a[e]; v[e + 4] = (bf16)c[e]; }
    *(bf16x8*)(dst + i) = v;
}

// ---------------------------------------------------------------- GEMM (NT, bf16, K=1024)
// MODE 0: QKV (N=3072): q=(acc+bq)*QSCALE -> qb ; k=acc+bk -> kb ; v=acc+bv -> vtb (transposed per head)
// MODE 1: proj (N=1024): f32 out = acc + bp
template <int MODE>
__global__ __launch_bounds__(256) void gemm_nt(
    const bf16* __restrict__ A, const bf16* __restrict__ B,
    const float* __restrict__ bias0, const float* __restrict__ bias1,
    const float* __restrict__ bias2,
    bf16* __restrict__ q_out, bf16* __restrict__ k_out, bf16* __restrict__ vt_out,
    float* __restrict__ f_out)
{
    constexpr int K = 1024;
    const int tid = threadIdx.x;
    const int lane = tid & 63;
    const int wid = tid >> 6;
    const int wr = wid >> 1, wc = wid & 1;
    const int m0 = blockIdx.y * 128, n0 = blockIdx.x * 128;

    __shared__ __align__(16) bf16 As[128 * 32];
    __shared__ __align__(16) bf16 Bs[128 * 32];

    f32x4 acc[4][4];
    #pragma unroll
    for (int i = 0; i < 4; ++i)
        #pragma unroll
        for (int j = 0; j < 4; ++j)
            #pragma unroll
            for (int e = 0; e < 4; ++e) acc[i][j][e] = 0.f;

    const bf16* ga = A + (m0 + (tid >> 2)) * K + (tid & 3) * 8;
    const bf16* gb = B + (n0 + (tid >> 2)) * K + (tid & 3) * 8;
    bf16* lA = As + tid * 8;
    bf16* lB = Bs + tid * 8;
    const bf16* fa = As + (wr * 64 + (lane & 15)) * 32 + (lane >> 4) * 8;
    const bf16* fb = Bs + (wc * 64 + (lane & 15)) * 32 + (lane >> 4) * 8;

    for (int kt = 0; kt < K; kt += 32) {
        GLDS16(ga + kt, lA);
        GLDS16(ga + kt + 64 * K, lA + 64 * 32);
        GLDS16(gb + kt, lB);
        GLDS16(gb + kt + 64 * K, lB + 64 * 32);
        __syncthreads();
        bf16x8 af[4], bfr[4];
        #pragma unroll
        for (int i = 0; i < 4; ++i) af[i] = *(const bf16x8*)(fa + i * 512);
        #pragma unroll
        for (int j = 0; j < 4; ++j) bfr[j] = *(const bf16x8*)(fb + j * 512);
        #pragma unroll
        for (int i = 0; i < 4; ++i)
            #pragma unroll
            for (int j = 0; j < 4; ++j)
                acc[i][j] = __builtin_amdgcn_mfma_f32_16x16x32_bf16(af[i], bfr[j], acc[i][j], 0, 0, 0);
        __syncthreads();
    }

    // epilogue: C/D layout col = lane&15, row = (lane>>4)*4 + reg  [m89-verified]
    #pragma unroll
    for (int i = 0; i < 4; ++i) {
        #pragma unroll
        for (int j = 0; j < 4; ++j) {
            #pragma unroll
            for (int r = 0; r < 4; ++r) {
                int m = m0 + wr * 64 + i * 16 + (lane >> 4) * 4 + r;
                int n = n0 + wc * 64 + j * 16 + (lane & 15);
                float v = acc[i][j][r];
                if (MODE == 0) {
                    if (n0 < 1024) {
                        q_out[m * 1024 + n] = (bf16)((v + bias0[n]) * QSCALE);
                    } else if (n0 < 2048) {
                        int nn = n - 1024;
                        k_out[m * 1024 + nn] = (bf16)(v + bias1[nn]);
                    } else {
                        int nn = n - 2048;
                        int hl = nn >> 7, d = nn & 127;
                        int bb = m >> 10, t = m & 1023;
                        vt_out[((bb * 8 + hl) * 128 + d) * 1024 + t] = (bf16)(v + bias2[nn]);
                    }
                } else {
                    f_out[m * 1024 + n] = v + bias0[n];
                }
            }
        }
    }
}

// ---------------------------------------------------------------- flash attention
// grid: 512 = B(8) * H(8) * (T/128); block: 4 waves, each owns 32 q-rows.
// q pre-scaled by log2(e)/sqrt(D) -> softmax in exp2 units.
__global__ __launch_bounds__(256) void attn_kernel(
    const bf16* __restrict__ qb, const bf16* __restrict__ kb,
    const bf16* __restrict__ vtb, const int* __restrict__ mask,
    bf16* __restrict__ yb)
{
    const int tid = threadIdx.x;
    const int lane = tid & 63;
    const int wid = tid >> 6;
    const int bid = blockIdx.x;
    const int b = bid >> 6;
    const int h = (bid >> 3) & 7;
    const int qt = bid & 7;
    const int m0 = b * 1024 + qt * 128;
    const int bh = b * 8 + h;

    __shared__ __align__(16) char smem[49408];
    bf16* Qs = (bf16*)smem;            // 32 KB (prologue only, overlaps Ks+Vs)
    bf16* Ks = (bf16*)smem;            // 16 KB  [64 t' rows][128 d]
    bf16* Vs = (bf16*)(smem + 16384);  // 16 KB  [128 d rows][64 t']  (V^T)
    bf16* Ps = (bf16*)(smem + 32768);  // 16 KB  per-wave [32][64]
    int*  Mk = (int*)(smem + 49152);   // 256 B

    // stage Q tile (128 x 128)
    #pragma unroll
    for (int n = 0; n < 8; ++n)
        GLDS16(qb + (m0 + n * 16 + (tid >> 4)) * 1024 + h * 128 + (tid & 15) * 8,
               (char*)Qs + n * 4096 + tid * 16);
    __syncthreads();

    bf16x8 qf[2][4];
    #pragma unroll
    for (int i = 0; i < 2; ++i)
        #pragma unroll
        for (int kc = 0; kc < 4; ++kc)
            qf[i][kc] = *(const bf16x8*)((const char*)Qs +
                (wid * 32 + i * 16 + (lane & 15)) * 256 + kc * 64 + (lane >> 4) * 16);
    __syncthreads();

    f32x4 o[2][8];
    #pragma unroll
    for (int i = 0; i < 2; ++i)
        #pragma unroll
        for (int jd = 0; jd < 8; ++jd)
            #pragma unroll
            for (int e = 0; e < 4; ++e) o[i][jd][e] = 0.f;
    float m_run[2][4], l_run[2][4];
    #pragma unroll
    for (int i = 0; i < 2; ++i)
        #pragma unroll
        for (int r = 0; r < 4; ++r) { m_run[i][r] = -1e30f; l_run[i][r] = 0.f; }

    for (int kt = 0; kt < 1024; kt += 64) {
        #pragma unroll
        for (int n = 0; n < 4; ++n)
            GLDS16(kb + (b * 1024 + kt + n * 16 + (tid >> 4)) * 1024 + h * 128 + (tid & 15) * 8,
                   (char*)Ks + n * 4096 + tid * 16);
        #pragma unroll
        for (int n = 0; n < 4; ++n)
            GLDS16(vtb + (bh * 128 + n * 32 + (tid >> 3)) * 1024 + kt + (tid & 7) * 8,
                   (char*)Vs + n * 4096 + tid * 16);
        if (tid < 64) GLDS4(mask + b * 1024 + kt + tid, (char*)Mk + tid * 4);
        __syncthreads();

        // S = Q K^T  (32 q-rows x 64 t' per wave)
        f32x4 s[2][4];
        #pragma unroll
        for (int i = 0; i < 2; ++i)
            #pragma unroll
            for (int j = 0; j < 4; ++j)
                #pragma unroll
                for (int e = 0; e < 4; ++e) s[i][j][e] = 0.f;
        #pragma unroll
        for (int kc = 0; kc < 4; ++kc) {
            bf16x8 kf[4];
            #pragma unroll
            for (int j = 0; j < 4; ++j)
                kf[j] = *(const bf16x8*)((const char*)Ks +
                    (j * 16 + (lane & 15)) * 256 + kc * 64 + (lane >> 4) * 16);
            #pragma unroll
            for (int i = 0; i < 2; ++i)
                #pragma unroll
                for (int j = 0; j < 4; ++j)
                    s[i][j] = __builtin_amdgcn_mfma_f32_16x16x32_bf16(qf[i][kc], kf[j], s[i][j], 0, 0, 0);
        }

        // mask (key positions)
        int mv[4];
        #pragma unroll
        for (int j = 0; j < 4; ++j) mv[j] = Mk[j * 16 + (lane & 15)];
        #pragma unroll
        for (int j = 0; j < 4; ++j)
            if (mv[j] == 0) {
                #pragma unroll
                for (int i = 0; i < 2; ++i)
                    #pragma unroll
                    for (int e = 0; e < 4; ++e) s[i][j][e] = -1e30f;
            }

        // online softmax per 16-row block
        #pragma unroll
        for (int i = 0; i < 2; ++i) {
            float tm[4], corr[4], rs[4];
            #pragma unroll
            for (int r = 0; r < 4; ++r)
                tm[r] = fmaxf(fmaxf(s[i][0][r], s[i][1][r]), fmaxf(s[i][2][r], s[i][3][r]));
            #pragma unroll
            for (int off = 8; off >= 1; off >>= 1)
                #pragma unroll
                for (int r = 0; r < 4; ++r) tm[r] = fmaxf(tm[r], __shfl_xor(tm[r], off));
            #pragma unroll
            for (int r = 0; r < 4; ++r) {
                float mn = fmaxf(m_run[i][r], tm[r]);
                corr[r] = __builtin_amdgcn_exp2f(m_run[i][r] - mn);
                m_run[i][r] = mn;
                rs[r] = 0.f;
            }
            #pragma unroll
            for (int j = 0; j < 4; ++j)
                #pragma unroll
                for (int r = 0; r < 4; ++r) {
                    float p = __builtin_amdgcn_exp2f(s[i][j][r] - m_run[i][r]);
                    s[i][j][r] = p;
                    rs[r] += p;
                }
            #pragma unroll
            for (int off = 8; off >= 1; off >>= 1)
                #pragma unroll
                for (int r = 0; r < 4; ++r) rs[r] += __shfl_xor(rs[r], off);
            #pragma unroll
            for (int r = 0; r < 4; ++r) l_run[i][r] = l_run[i][r] * corr[r] + rs[r];
            #pragma unroll
            for (int jd = 0; jd < 8; ++jd)
                #pragma unroll
                for (int r = 0; r < 4; ++r) o[i][jd][r] *= corr[r];
            // P -> LDS (per-wave region), C-layout row=(lane>>4)*4+r, col=j*16+(lane&15)
            #pragma unroll
            for (int j = 0; j < 4; ++j)
                #pragma unroll
                for (int r = 0; r < 4; ++r)
                    Ps[wid * 2048 + (i * 16 + (lane >> 4) * 4 + r) * 64 + j * 16 + (lane & 15)] =
                        (bf16)s[i][j][r];
        }

        // O += P V   (A = P from LDS, B = V^T tile)
        #pragma unroll
        for (int k2 = 0; k2 < 2; ++k2) {
            bf16x8 pa[2];
            #pragma unroll
            for (int i = 0; i < 2; ++i)
                pa[i] = *(const bf16x8*)((const char*)Ps +
                    wid * 4096 + (i * 16 + (lane & 15)) * 128 + k2 * 64 + (lane >> 4) * 16);
            #pragma unroll
            for (int jd = 0; jd < 8; ++jd) {
                bf16x8 vf = *(const bf16x8*)((const char*)Vs +
                    (jd * 16 + (lane & 15)) * 128 + k2 * 64 + (lane >> 4) * 16);
                #pragma unroll
                for (int i = 0; i < 2; ++i)
                    o[i][jd] = __builtin_amdgcn_mfma_f32_16x16x32_bf16(pa[i], vf, o[i][jd], 0, 0, 0);
            }
        }
        __syncthreads();
    }

    // epilogue: normalize and store y (bf16)
    #pragma unroll
    for (int i = 0; i < 2; ++i) {
        float inv[4];
        #pragma unroll
        for (int r = 0; r < 4; ++r) inv[r] = 1.0f / fmaxf(l_run[i][r], 1e-30f);
        #pragma unroll
        for (int jd = 0; jd < 8; ++jd)
            #pragma unroll
            for (int r = 0; r < 4; ++r)
                yb[(m0 + wid * 32 + i * 16 + (lane >> 4) * 4 + r) * 1024 +
                   h * 128 + jd * 16 + (lane & 15)] = (bf16)(o[i][jd][r] * inv[r]);
    }
}

// ---------------------------------------------------------------- launch
extern "C" void kernel_launch(void* const* d_in, const int* in_sizes, int n_in,
                              void* d_out, int out_size, void* d_ws, size_t ws_size,
                              hipStream_t stream)
{
    (void)in_sizes; (void)n_in; (void)out_size; (void)ws_size;
    const float* x  = (const float*)d_in[0];
    const int* mask = (const int*)d_in[1];
    const float* Wq = (const float*)d_in[2];
    const float* bq = (const float*)d_in[3];
    const float* Wk = (const float*)d_in[4];
    const float* bk = (const float*)d_in[5];
    const float* Wv = (const float*)d_in[6];
    const float* bv = (const float*)d_in[7];
    const float* Wp = (const float*)d_in[8];
    const float* bp = (const float*)d_in[9];
    float* out = (float*)d_out;

    // workspace carve (88 MB total)
    char* ws = (char*)d_ws;
    bf16* xb    = (bf16*)(ws);                      // 16 MB  x as bf16 (8192 x 1024)
    bf16* wqkvb = (bf16*)(ws + (16u << 20));        //  6 MB  [Wq;Wk;Wv] (3072 x 1024)
    bf16* wpb   = (bf16*)(ws + (22u << 20));        //  2 MB  Wp (1024 x 1024)
    bf16* qbuf  = (bf16*)(ws + (24u << 20));        // 16 MB  q (scaled), (8192 x 1024)
    bf16* kbuf  = (bf16*)(ws + (40u << 20));        // 16 MB  k (8192 x 1024)
    bf16* vtb   = (bf16*)(ws + (56u << 20));        // 16 MB  v^T per (b,h): (64*128 x 1024)
    bf16* ybuf  = (bf16*)(ws + (72u << 20));        // 16 MB  attention out (8192 x 1024)

    convert_kernel<<<6144, 256, 0, stream>>>(x, Wq, Wk, Wv, Wp, xb, wqkvb, wpb);
    gemm_nt<0><<<dim3(24, 64), 256, 0, stream>>>(xb, wqkvb, bq, bk, bv,
                                                 qbuf, kbuf, vtb, nullptr);
    attn_kernel<<<512, 256, 0, stream>>>(qbuf, kbuf, vtb, mask, ybuf);
    gemm_nt<1><<<dim3(8, 64), 256, 0, stream>>>(ybuf, wpb, bp, nullptr, nullptr,
                                                nullptr, nullptr, nullptr, out);
}

// Round 2
// 216.954 us; speedup vs baseline: 1.2009x; 1.2009x over previous
//
#include <hip/hip_runtime.h>

typedef __bf16 bf16;
typedef __attribute__((ext_vector_type(8))) bf16 bf16x8;
typedef __attribute__((ext_vector_type(4))) float f32x4;

// async global->LDS (LDS dest is wave-uniform base + lane*16; ours is base + tid*16)
#define GLDS16(g, l) __builtin_amdgcn_global_load_lds( \
    (const __attribute__((address_space(1))) void*)(g), \
    (__attribute__((address_space(3))) void*)(l), 16, 0, 0)

// log2(e)/sqrt(128): folded into q at the QKV epilogue so softmax uses exp2 directly
#define QSCALE 0.12751744f

// ---------------------------------------------------------------- convert f32->bf16
__global__ __launch_bounds__(256) void convert_kernel(
    const float* __restrict__ x, const float* __restrict__ wq,
    const float* __restrict__ wk, const float* __restrict__ wv,
    const float* __restrict__ wp,
    bf16* __restrict__ xb, bf16* __restrict__ wqkvb, bf16* __restrict__ wpb)
{
    int bid = blockIdx.x;
    const float* src; bf16* dst; int base;
    if (bid < 4096)      { src = x;  dst = xb;              base = bid * 2048; }
    else if (bid < 4608) { src = wq; dst = wqkvb;           base = (bid - 4096) * 2048; }
    else if (bid < 5120) { src = wk; dst = wqkvb + 1048576; base = (bid - 4608) * 2048; }
    else if (bid < 5632) { src = wv; dst = wqkvb + 2097152; base = (bid - 5120) * 2048; }
    else                 { src = wp; dst = wpb;             base = (bid - 5632) * 2048; }
    int i = base + threadIdx.x * 8;
    const f32x4* s4 = (const f32x4*)(src + i);
    f32x4 a = s4[0], c = s4[1];
    bf16x8 v;
    #pragma unroll
    for (int e = 0; e < 4; ++e) { v[e] = (bf16)a[e]; v[e + 4] = (bf16)c[e]; }
    *(bf16x8*)(dst + i) = v;
}

// ---------------------------------------------------------------- GEMM (NT, bf16, K=1024)
// MODE 0: QKV (N=3072): q=(acc+bq)*QSCALE -> qb ; k=acc+bk -> kb ; v=acc+bv -> vtb (transposed per head)
// MODE 1: proj (N=1024): f32 out = acc + bp
template <int MODE>
__global__ __launch_bounds__(256) void gemm_nt(
    const bf16* __restrict__ A, const bf16* __restrict__ B,
    const float* __restrict__ bias0, const float* __restrict__ bias1,
    const float* __restrict__ bias2,
    bf16* __restrict__ q_out, bf16* __restrict__ k_out, bf16* __restrict__ vt_out,
    float* __restrict__ f_out)
{
    constexpr int K = 1024;
    const int tid = threadIdx.x;
    const int lane = tid & 63;
    const int wid = tid >> 6;
    const int wr = wid >> 1, wc = wid & 1;
    const int m0 = blockIdx.y * 128, n0 = blockIdx.x * 128;

    __shared__ __align__(16) bf16 As[128 * 32];
    __shared__ __align__(16) bf16 Bs[128 * 32];

    f32x4 acc[4][4];
    #pragma unroll
    for (int i = 0; i < 4; ++i)
        #pragma unroll
        for (int j = 0; j < 4; ++j)
            #pragma unroll
            for (int e = 0; e < 4; ++e) acc[i][j][e] = 0.f;

    const bf16* ga = A + (m0 + (tid >> 2)) * K + (tid & 3) * 8;
    const bf16* gb = B + (n0 + (tid >> 2)) * K + (tid & 3) * 8;
    bf16* lA = As + tid * 8;
    bf16* lB = Bs + tid * 8;
    const bf16* fa = As + (wr * 64 + (lane & 15)) * 32 + (lane >> 4) * 8;
    const bf16* fb = Bs + (wc * 64 + (lane & 15)) * 32 + (lane >> 4) * 8;

    for (int kt = 0; kt < K; kt += 32) {
        GLDS16(ga + kt, lA);
        GLDS16(ga + kt + 64 * K, lA + 64 * 32);
        GLDS16(gb + kt, lB);
        GLDS16(gb + kt + 64 * K, lB + 64 * 32);
        __syncthreads();
        bf16x8 af[4], bfr[4];
        #pragma unroll
        for (int i = 0; i < 4; ++i) af[i] = *(const bf16x8*)(fa + i * 512);
        #pragma unroll
        for (int j = 0; j < 4; ++j) bfr[j] = *(const bf16x8*)(fb + j * 512);
        #pragma unroll
        for (int i = 0; i < 4; ++i)
            #pragma unroll
            for (int j = 0; j < 4; ++j)
                acc[i][j] = __builtin_amdgcn_mfma_f32_16x16x32_bf16(af[i], bfr[j], acc[i][j], 0, 0, 0);
        __syncthreads();
    }

    // epilogue: C/D layout col = lane&15, row = (lane>>4)*4 + reg  [m89-verified]
    #pragma unroll
    for (int i = 0; i < 4; ++i) {
        #pragma unroll
        for (int j = 0; j < 4; ++j) {
            #pragma unroll
            for (int r = 0; r < 4; ++r) {
                int m = m0 + wr * 64 + i * 16 + (lane >> 4) * 4 + r;
                int n = n0 + wc * 64 + j * 16 + (lane & 15);
                float v = acc[i][j][r];
                if (MODE == 0) {
                    if (n0 < 1024) {
                        q_out[m * 1024 + n] = (bf16)((v + bias0[n]) * QSCALE);
                    } else if (n0 < 2048) {
                        int nn = n - 1024;
                        k_out[m * 1024 + nn] = (bf16)(v + bias1[nn]);
                    } else {
                        int nn = n - 2048;
                        int hl = nn >> 7, d = nn & 127;
                        int bb = m >> 10, t = m & 1023;
                        vt_out[((bb * 8 + hl) * 128 + d) * 1024 + t] = (bf16)(v + bias2[nn]);
                    }
                } else {
                    f_out[m * 1024 + n] = v + bias0[n];
                }
            }
        }
    }
}

// ---------------------------------------------------------------- flash attention v2
// grid: 1024 = B(8)*H(8)*(T/64); 4 waves/block, each wave owns 16 q-rows.
// LDS = 40960 B exactly -> 4 blocks/CU; __launch_bounds__(256,4) caps VGPR<=128
// -> 16 waves/CU. K/V/P tiles XOR-swizzled (chunk ^= row&7) to kill the
// stride-128B/256B bank conflicts; swizzle applied on the GLOBAL source addr
// (global_load_lds writes linearly) and on every ds_read (m173/T2 pattern).
__global__ __launch_bounds__(256, 4) void attn_kernel(
    const bf16* __restrict__ qb, const bf16* __restrict__ kb,
    const bf16* __restrict__ vtb, const int* __restrict__ mask,
    bf16* __restrict__ yb)
{
    const int tid = threadIdx.x;
    const int lane = tid & 63;
    const int wid = tid >> 6;
    // XCD chunk swizzle (bijective: 1024 = 8*128): all 16 q-tiles of a (b,h)
    // land on one XCD -> K/V stay in that XCD's L2.
    const int g = blockIdx.x;
    const int orig = (g & 7) * 128 + (g >> 3);
    const int bh = orig >> 4;
    const int qt = orig & 15;
    const int b = bh >> 3;
    const int h = bh & 7;
    const int m0 = b * 1024 + qt * 64;

    __shared__ __align__(16) char smem[40960];
    bf16* Ks = (bf16*)smem;              // 16 KB [64 t'][128 d] swizzled
    bf16* Vs = (bf16*)(smem + 16384);    // 16 KB [128 d][64 t'] swizzled (V^T)
    // Ps at smem+32768: 8 KB, per-wave [16][64] swizzled

    // Q fragments straight from global (one-time, L2-cached)
    bf16x8 qf[4];
    #pragma unroll
    for (int kc = 0; kc < 4; ++kc)
        qf[kc] = *(const bf16x8*)(qb + (m0 + wid * 16 + (lane & 15)) * 1024 +
                                  h * 128 + kc * 32 + (lane >> 4) * 8);

    f32x4 o[8];
    #pragma unroll
    for (int jd = 0; jd < 8; ++jd)
        #pragma unroll
        for (int e = 0; e < 4; ++e) o[jd][e] = 0.f;
    float m_run[4], l_run[4];
    #pragma unroll
    for (int r = 0; r < 4; ++r) { m_run[r] = -1e30f; l_run[r] = 0.f; }

    for (int kt = 0; kt < 1024; kt += 64) {
        // stage K: 64 rows x 256B; lane covers row (tid>>4), phys chunk tid&15,
        // global supplies logical chunk (tid&15)^((tid>>4)&7)
        #pragma unroll
        for (int n = 0; n < 4; ++n)
            GLDS16(kb + (b * 1024 + kt + n * 16 + (tid >> 4)) * 1024 + h * 128 +
                       (((tid & 15) ^ ((tid >> 4) & 7)) * 8),
                   (char*)Ks + n * 4096 + tid * 16);
        // stage V^T: 128 rows x 128B; row n*32+(tid>>3), phys chunk tid&7
        #pragma unroll
        for (int n = 0; n < 4; ++n)
            GLDS16(vtb + (bh * 128 + n * 32 + (tid >> 3)) * 1024 + kt +
                       (((tid & 7) ^ ((tid >> 3) & 7)) * 8),
                   (char*)Vs + n * 4096 + tid * 16);
        __syncthreads();

        // S = Q K^T  (16 q-rows x 64 t' per wave)
        f32x4 s[4];
        #pragma unroll
        for (int j = 0; j < 4; ++j)
            #pragma unroll
            for (int e = 0; e < 4; ++e) s[j][e] = 0.f;
        #pragma unroll
        for (int kc = 0; kc < 4; ++kc) {
            bf16x8 kf[4];
            #pragma unroll
            for (int j = 0; j < 4; ++j)
                kf[j] = *(const bf16x8*)((const char*)Ks +
                    (j * 16 + (lane & 15)) * 256 +
                    (((kc * 4 + (lane >> 4)) ^ (lane & 7)) * 16));
            #pragma unroll
            for (int j = 0; j < 4; ++j)
                s[j] = __builtin_amdgcn_mfma_f32_16x16x32_bf16(qf[kc], kf[j], s[j], 0, 0, 0);
        }

        // mask (key positions); all-ones in this problem but must be honored
        #pragma unroll
        for (int j = 0; j < 4; ++j)
            if (mask[b * 1024 + kt + j * 16 + (lane & 15)] == 0) {
                #pragma unroll
                for (int e = 0; e < 4; ++e) s[j][e] = -1e30f;
            }

        // online softmax (rows r=0..3 of this lane's quad-group)
        float tm[4], corr[4], rs[4];
        #pragma unroll
        for (int r = 0; r < 4; ++r)
            tm[r] = fmaxf(fmaxf(s[0][r], s[1][r]), fmaxf(s[2][r], s[3][r]));
        #pragma unroll
        for (int off = 8; off >= 1; off >>= 1)
            #pragma unroll
            for (int r = 0; r < 4; ++r) tm[r] = fmaxf(tm[r], __shfl_xor(tm[r], off));
        #pragma unroll
        for (int r = 0; r < 4; ++r) {
            float mn = fmaxf(m_run[r], tm[r]);
            corr[r] = __builtin_amdgcn_exp2f(m_run[r] - mn);
            m_run[r] = mn;
            rs[r] = 0.f;
        }
        #pragma unroll
        for (int j = 0; j < 4; ++j)
            #pragma unroll
            for (int r = 0; r < 4; ++r) {
                float p = __builtin_amdgcn_exp2f(s[j][r] - m_run[r]);
                s[j][r] = p;
                rs[r] += p;
            }
        #pragma unroll
        for (int off = 8; off >= 1; off >>= 1)
            #pragma unroll
            for (int r = 0; r < 4; ++r) rs[r] += __shfl_xor(rs[r], off);
        #pragma unroll
        for (int r = 0; r < 4; ++r) l_run[r] = l_run[r] * corr[r] + rs[r];
        #pragma unroll
        for (int jd = 0; jd < 8; ++jd)
            #pragma unroll
            for (int r = 0; r < 4; ++r) o[jd][r] *= corr[r];

        // P -> per-wave LDS [16][64] bf16, swizzled like K/V
        #pragma unroll
        for (int j = 0; j < 4; ++j)
            #pragma unroll
            for (int r = 0; r < 4; ++r) {
                int row = (lane >> 4) * 4 + r;
                int col = j * 16 + (lane & 15);
                *(bf16*)((char*)smem + 32768 + wid * 2048 + row * 128 +
                         (((col >> 3) ^ (row & 7)) * 16) + (col & 7) * 2) = (bf16)s[j][r];
            }

        // O += P V
        #pragma unroll
        for (int k2 = 0; k2 < 2; ++k2) {
            bf16x8 pa = *(const bf16x8*)((const char*)smem + 32768 + wid * 2048 +
                (lane & 15) * 128 + (((k2 * 4 + (lane >> 4)) ^ (lane & 7)) * 16));
            #pragma unroll
            for (int jd = 0; jd < 8; ++jd) {
                bf16x8 vf = *(const bf16x8*)((const char*)Vs +
                    (jd * 16 + (lane & 15)) * 128 +
                    (((k2 * 4 + (lane >> 4)) ^ (lane & 7)) * 16));
                o[jd] = __builtin_amdgcn_mfma_f32_16x16x32_bf16(pa, vf, o[jd], 0, 0, 0);
            }
        }
        __syncthreads();
    }

    // epilogue: normalize and store y (bf16)
    float inv[4];
    #pragma unroll
    for (int r = 0; r < 4; ++r) inv[r] = 1.0f / fmaxf(l_run[r], 1e-30f);
    #pragma unroll
    for (int jd = 0; jd < 8; ++jd)
        #pragma unroll
        for (int r = 0; r < 4; ++r)
            yb[(m0 + wid * 16 + (lane >> 4) * 4 + r) * 1024 +
               h * 128 + jd * 16 + (lane & 15)] = (bf16)(o[jd][r] * inv[r]);
}

// ---------------------------------------------------------------- launch
extern "C" void kernel_launch(void* const* d_in, const int* in_sizes, int n_in,
                              void* d_out, int out_size, void* d_ws, size_t ws_size,
                              hipStream_t stream)
{
    (void)in_sizes; (void)n_in; (void)out_size; (void)ws_size;
    const float* x  = (const float*)d_in[0];
    const int* mask = (const int*)d_in[1];
    const float* Wq = (const float*)d_in[2];
    const float* bq = (const float*)d_in[3];
    const float* Wk = (const float*)d_in[4];
    const float* bk = (const float*)d_in[5];
    const float* Wv = (const float*)d_in[6];
    const float* bv = (const float*)d_in[7];
    const float* Wp = (const float*)d_in[8];
    const float* bp = (const float*)d_in[9];
    float* out = (float*)d_out;

    // workspace carve (88 MB total)
    char* ws = (char*)d_ws;
    bf16* xb    = (bf16*)(ws);                      // 16 MB  x as bf16 (8192 x 1024)
    bf16* wqkvb = (bf16*)(ws + (16u << 20));        //  6 MB  [Wq;Wk;Wv] (3072 x 1024)
    bf16* wpb   = (bf16*)(ws + (22u << 20));        //  2 MB  Wp (1024 x 1024)
    bf16* qbuf  = (bf16*)(ws + (24u << 20));        // 16 MB  q (scaled), (8192 x 1024)
    bf16* kbuf  = (bf16*)(ws + (40u << 20));        // 16 MB  k (8192 x 1024)
    bf16* vtb   = (bf16*)(ws + (56u << 20));        // 16 MB  v^T per (b,h): (64*128 x 1024)
    bf16* ybuf  = (bf16*)(ws + (72u << 20));        // 16 MB  attention out (8192 x 1024)

    convert_kernel<<<6144, 256, 0, stream>>>(x, Wq, Wk, Wv, Wp, xb, wqkvb, wpb);
    gemm_nt<0><<<dim3(24, 64), 256, 0, stream>>>(xb, wqkvb, bq, bk, bv,
                                                 qbuf, kbuf, vtb, nullptr);
    attn_kernel<<<1024, 256, 0, stream>>>(qbuf, kbuf, vtb, mask, ybuf);
    gemm_nt<1><<<dim3(8, 64), 256, 0, stream>>>(ybuf, wpb, bp, nullptr, nullptr,
                                                nullptr, nullptr, nullptr, out);
}